// Round 2
// baseline (289.138 us; speedup 1.0000x reference)
//
#include <hip/hip_runtime.h>
#include <float.h>

// VectorQuantizer: B=16,T=4096,D=256,K=1024 fp32.
// Round 4: cached reg-staging (fixes round-3 FETCH explosion: global_load_lds
//   codebook re-reads missed L2/L3), XOR-swizzled ds_write/ds_read (0 bank
//   conflicts, verified round 3), double-buffered 1-barrier-per-stage pipeline
//   with T14 issue-early/write-late staging, compile-time stage indexing
//   (fixes round-3 bfrag scratch spill, VGPR 84 -> register-resident).
//   Score space: score = x.c - 0.5*c2  (argmin d2 == argmax score).
//   Rescue: 32 tokens/block-iter (4x less codebook traffic), barrier-light merge.

typedef _Float16 f16;
typedef f16 f16x8 __attribute__((ext_vector_type(8)));
typedef f16 f16x4 __attribute__((ext_vector_type(4)));
typedef float f32x4 __attribute__((ext_vector_type(4)));

#define DDIM    256
#define KCODES  1024
#define NTOK    65536
#define SMARGIN 0.1f   // score-space margin; == 0.2 in d2 units (d2 gap = 2*score gap)

// swizzled LDS byte offset for (row, col-byte) in a 128-row x 128B tile
#define ASW(r, cbyte) ((r) * 128 + ((cbyte) ^ (((r) & 7) << 4)))

// ---------------- prep: codebook fp32->f16, c2, zero counter ----------------
__global__ __launch_bounds__(256) void vq_prep(const float* __restrict__ cb,
                                               f16* __restrict__ ch,
                                               float* __restrict__ c2,
                                               unsigned* __restrict__ count) {
    const int k    = blockIdx.x * 4 + (threadIdx.x >> 6);
    const int lane = threadIdx.x & 63;
    const float4 v = *(const float4*)(cb + (size_t)k * DDIM + 4 * lane);
    f16x4 h; h[0] = (f16)v.x; h[1] = (f16)v.y; h[2] = (f16)v.z; h[3] = (f16)v.w;
    *(f16x4*)(ch + (size_t)k * DDIM + 4 * lane) = h;
    float s = v.x * v.x + v.y * v.y + v.z * v.z + v.w * v.w;
    #pragma unroll
    for (int off = 32; off > 0; off >>= 1) s += __shfl_down(s, off, 64);
    if (lane == 0) c2[k] = s;
    if (blockIdx.x == 0 && threadIdx.x == 0) *count = 0u;
}

// ---------------- main: MFMA distances + fused argmax(score) + gather ----------------
// Stage tile: 128 code rows x 64 f16 (128 B/row), double-buffered, XOR-swizzled:
//   LDS byte (r, C ^ ((r&7)<<4)) holds global element byte (r, C).
//   write: granule g = t + 256*i -> row g>>3, col-byte (g&7)*16 (conflict-free b128)
//   read : byte = R*128 + (((kk<<6)|(q<<4)) ^ ((R&7)<<4))   (conflict-free b128)
__global__ __launch_bounds__(256, 2) void vq_main(const float* __restrict__ xg,
                                                  const f16* __restrict__ ch,
                                                  const float* __restrict__ c2,
                                                  const float* __restrict__ cb,
                                                  float* __restrict__ out,
                                                  unsigned* __restrict__ count,
                                                  unsigned* __restrict__ list) {
    __shared__ f16   As[2 * 8192];             // 2 x (128 x 64) f16 = 32 KB
    __shared__ float c2s[KCODES];
    __shared__ float wmv[2][128];              // per code-half best score
    __shared__ int   wmi[2][128];
    __shared__ float wms[2][128];              // per code-half second score
    __shared__ float runv[128], runs[128];
    __shared__ int   runi[128];
    __shared__ int   idx_s[128];

    const int t    = threadIdx.x;
    const int wave = t >> 6, lane = t & 63;
    const int wm   = wave >> 1;                // code-half (M)
    const int tn   = wave & 1;                 // token-half (N)
    const int q    = lane >> 4;                // operand quad
    const int m16  = lane & 15;
    const int tok0 = blockIdx.x * 128;
    const int swz  = (m16 & 7) << 4;           // read-side swizzle (row&7 == m16&7)
    const int srow = t >> 3;                   // staging: rows srow + 32*i
    const int sc16 = t & 7;                    // staging: col granule (16B)

    // ---- load token B-fragments, fp32 -> f16 in registers (once) ----
    f16x8 bfrag[4][8];
    #pragma unroll
    for (int ti = 0; ti < 4; ++ti) {
        const size_t row = (size_t)(tok0 + tn * 64 + ti * 16 + m16) * DDIM;
        #pragma unroll
        for (int ks = 0; ks < 8; ++ks) {
            const float* p = xg + row + ks * 32 + q * 8;
            const float4 u0 = *(const float4*)(p);
            const float4 u1 = *(const float4*)(p + 4);
            f16x8 b;
            b[0] = (f16)u0.x; b[1] = (f16)u0.y; b[2] = (f16)u0.z; b[3] = (f16)u0.w;
            b[4] = (f16)u1.x; b[5] = (f16)u1.y; b[6] = (f16)u1.z; b[7] = (f16)u1.w;
            bfrag[ti][ks] = b;
        }
    }

    *(float4*)&c2s[t * 4] = *(const float4*)(c2 + t * 4);
    if (t < 128) { runv[t] = -FLT_MAX; runs[t] = -FLT_MAX; runi[t] = 0; }

    // prologue: issue stage (0,0) loads into regs
    f16x8 sreg[4];
    #pragma unroll
    for (int i = 0; i < 4; ++i)
        sreg[i] = *(const f16x8*)(ch + (size_t)(srow + 32 * i) * DDIM + sc16 * 8);
    __syncthreads();                           // c2s / runv init visible

    for (int nc = 0; nc < 8; ++nc) {
        f32x4 acc[4][4];                       // [ci][ti], init = -0.5*c2 (score space)
        #pragma unroll
        for (int ci = 0; ci < 4; ++ci) {
            f32x4 cv = *(const f32x4*)&c2s[nc * 128 + wm * 64 + ci * 16 + q * 4];
            cv = cv * -0.5f;
            #pragma unroll
            for (int ti = 0; ti < 4; ++ti) acc[ci][ti] = cv;
        }

        #pragma unroll
        for (int st = 0; st < 4; ++st) {       // BK=64 stages; buf parity == st&1
            // ---- write staged regs -> buf[st&1], swizzled (conflict-free) ----
            char* Ab = (char*)As + (st & 1) * 16384;
            #pragma unroll
            for (int i = 0; i < 4; ++i) {
                const int r = srow + 32 * i;
                *(f16x8*)(Ab + ASW(r, sc16 * 16)) = sreg[i];
            }
            // ---- issue next stage's loads (fly under this stage's MFMA) ----
            if (!(nc == 7 && st == 3)) {
                const int nn = nc + (st == 3 ? 1 : 0);
                const int ns = (st + 1) & 3;
                #pragma unroll
                for (int i = 0; i < 4; ++i)
                    sreg[i] = *(const f16x8*)(ch + (size_t)(nn * 128 + srow + 32 * i) * DDIM
                                              + ns * 64 + sc16 * 8);
            }
            __syncthreads();                   // buf[st&1] visible; dbuf covers WAR

            // ---- compute: ds_read (swizzled) + 32 MFMA ----
            const char* Ar = (const char*)As + (st & 1) * 16384;
            const int rbase = (wm * 64 + m16) * 128;
            #pragma unroll
            for (int kk = 0; kk < 2; ++kk) {
                const int col = ((kk << 6) | (q << 4)) ^ swz;
                f16x8 af[4];
                #pragma unroll
                for (int ci = 0; ci < 4; ++ci)
                    af[ci] = *(const f16x8*)(Ar + rbase + ci * 2048 + col);
                #pragma unroll
                for (int ci = 0; ci < 4; ++ci)
                    #pragma unroll
                    for (int ti = 0; ti < 4; ++ti)
                        acc[ci][ti] = __builtin_amdgcn_mfma_f32_16x16x32_f16(
                            af[ci], bfrag[ti][st * 2 + kk], acc[ci][ti], 0, 0, 0);
            }

            if (st == 3) {
                // ---- chunk epilogue: per-token top-2 (max score) over 128 codes ----
                const int kbase = nc * 128 + wm * 64;
                #pragma unroll
                for (int ti = 0; ti < 4; ++ti) {
                    float b1 = -FLT_MAX, b2 = -FLT_MAX; int i1 = 0;
                    #pragma unroll
                    for (int ci = 0; ci < 4; ++ci) {   // ascending code order
                        #pragma unroll
                        for (int r = 0; r < 4; ++r) {
                            const float v = acc[ci][ti][r];
                            const int   c = kbase + ci * 16 + q * 4 + r;
                            const bool gt = v > b1;    // strict: tie keeps lower index
                            b2 = fmaxf(b2, gt ? b1 : v);
                            i1 = gt ? c : i1;
                            b1 = gt ? v : b1;
                        }
                    }
                    #pragma unroll
                    for (int sft = 0; sft < 2; ++sft) {  // merge quads (l^16, l^32)
                        const int off = 16 << sft;
                        const float ob1 = __shfl_xor(b1, off, 64);
                        const float ob2 = __shfl_xor(b2, off, 64);
                        const int   oi1 = __shfl_xor(i1, off, 64);
                        const bool better = (ob1 > b1) || (ob1 == b1 && oi1 < i1);
                        b2 = fmaxf(fmaxf(b2, ob2), fminf(b1, ob1));
                        b1 = better ? ob1 : b1;
                        i1 = better ? oi1 : i1;
                    }
                    if (lane < 16) {
                        const int tl = tn * 64 + ti * 16 + m16;
                        wmv[wm][tl] = b1; wmi[wm][tl] = i1; wms[wm][tl] = b2;
                    }
                }
                __syncthreads();                // wmv visible
                if (t < 128) {                  // merge code-halves, fold into running
                    const float a1 = wmv[0][t], a2 = wms[0][t];
                    const int   ai = wmi[0][t];
                    const float b1_ = wmv[1][t], b2_ = wms[1][t];
                    const int   bi_ = wmi[1][t];
                    const bool bb = (b1_ > a1) || (b1_ == a1 && bi_ < ai);
                    const float c1 = bb ? b1_ : a1;
                    const int   ci_ = bb ? bi_ : ai;
                    const float cs = fmaxf(fmaxf(a2, b2_), fminf(a1, b1_));
                    const float r1 = runv[t];
                    runs[t] = fmaxf(fmaxf(runs[t], cs), fminf(r1, c1));
                    if (c1 > r1) { runv[t] = c1; runi[t] = ci_; }  // tie -> earlier chunk
                }
                // next chunk's first stage barrier orders the wmv rewrite
            }
        }
    }

    __syncthreads();
    if (t < 128) {
        idx_s[t] = runi[t];
        if (runv[t] - runs[t] < SMARGIN) {      // d2 gap = 2*(runv-runs) < 0.2
            const unsigned p = atomicAdd(count, 1u);
            list[p] = tok0 + t;
        }
    }
    __syncthreads();

    // gather epilogue: out[tok] = cb[argmin], coalesced float4
    #pragma unroll
    for (int i = 0; i < 32; ++i) {
        const int f   = i * 256 + t;           // 8192 float4 = 128 tok x 64
        const int tok = f >> 6, d4 = f & 63;
        const int code = idx_s[tok];
        const float4 v = *(const float4*)(cb + (size_t)code * DDIM + 4 * d4);
        *(float4*)(out + (size_t)(tok0 + tok) * DDIM + 4 * d4) = v;
    }
}

// ---------------- rescue: exact fp32 argmin for margin-flagged tokens ----------------
// 32 tokens per block-iteration (4x less codebook re-read than 8).
// Per-(code,token) fmaf chain: d4-major, .x->.w — identical order to verified version.
__global__ __launch_bounds__(256) void vq_rescue(const float* __restrict__ xg,
                                                 const float* __restrict__ cb,
                                                 const float* __restrict__ c2,
                                                 const unsigned* __restrict__ count,
                                                 const unsigned* __restrict__ list,
                                                 float* __restrict__ out) {
    __shared__ float xls[32][DDIM];            // 32 KB
    __shared__ float rv[4][32];
    __shared__ int   ri[4][32];
    __shared__ int   bidx[32];

    const int t = threadIdx.x;
    const int wave = t >> 6, lane = t & 63;
    const unsigned n = *count;

    for (unsigned base = blockIdx.x * 32; base < n; base += gridDim.x * 32) {
        const int nb = (int)min(32u, n - base);
        __syncthreads();                        // protect xls/rv/bidx reuse
        #pragma unroll
        for (int i = 0; i < 8; ++i) {
            const int f = t + 256 * i;          // 2048 float4 slots
            const int row = f >> 6, d4 = f & 63;
            if (row < nb)
                *(float4*)&xls[row][4 * d4] =
                    *(const float4*)(xg + (size_t)list[base + row] * DDIM + 4 * d4);
        }
        __syncthreads();

        float acc[4][32];
        #pragma unroll
        for (int j = 0; j < 4; ++j)
            #pragma unroll
            for (int tk = 0; tk < 32; ++tk) acc[j][tk] = 0.0f;

        for (int d4 = 0; d4 < 64; ++d4) {
            float4 cv[4];
            #pragma unroll
            for (int j = 0; j < 4; ++j)
                cv[j] = *(const float4*)(cb + (size_t)(4 * t + j) * DDIM + 4 * d4);
            #pragma unroll
            for (int tk = 0; tk < 32; ++tk) {
                const float4 xv = *(const float4*)&xls[tk][4 * d4];
                #pragma unroll
                for (int j = 0; j < 4; ++j) {
                    float a = acc[j][tk];       // sequential .x->.w: verified order
                    a = fmaf(cv[j].x, xv.x, a);
                    a = fmaf(cv[j].y, xv.y, a);
                    a = fmaf(cv[j].z, xv.z, a);
                    a = fmaf(cv[j].w, xv.w, a);
                    acc[j][tk] = a;
                }
            }
        }

        // per-token argmin: thread's 4 codes -> wave butterfly -> cross-wave merge
        #pragma unroll
        for (int tk = 0; tk < 32; ++tk) {
            if (tk < nb) {
                float b1 = FLT_MAX; int i1 = 0;
                #pragma unroll
                for (int j = 0; j < 4; ++j) {   // codes 4t..4t+3 ascending
                    const float d = fmaf(-2.0f, acc[j][tk], c2[4 * t + j]);
                    if (d < b1) { b1 = d; i1 = 4 * t + j; }
                }
                #pragma unroll
                for (int off = 32; off > 0; off >>= 1) {
                    const float ov = __shfl_xor(b1, off, 64);
                    const int   oi = __shfl_xor(i1, off, 64);
                    if (ov < b1 || (ov == b1 && oi < i1)) { b1 = ov; i1 = oi; }
                }
                if (lane == 0) { rv[wave][tk] = b1; ri[wave][tk] = i1; }
            }
        }
        __syncthreads();
        if (t < 32 && t < nb) {                 // ascending wave order: same tiebreak
            float bv = rv[0][t]; int bi = ri[0][t];
            #pragma unroll
            for (int w = 1; w < 4; ++w)
                if (rv[w][t] < bv || (rv[w][t] == bv && ri[w][t] < bi)) {
                    bv = rv[w][t]; bi = ri[w][t];
                }
            bidx[t] = bi;
        }
        __syncthreads();

        #pragma unroll
        for (int i = 0; i < 8; ++i) {
            const int f = t + 256 * i;
            const int row = f >> 6, d4 = f & 63;
            if (row < nb) {
                const int code = bidx[row];
                const float4 v = *(const float4*)(cb + (size_t)code * DDIM + 4 * d4);
                *(float4*)(out + (size_t)list[base + row] * DDIM + 4 * d4) = v;
            }
        }
    }
}

extern "C" void kernel_launch(void* const* d_in, const int* in_sizes, int n_in,
                              void* d_out, int out_size, void* d_ws, size_t ws_size,
                              hipStream_t stream) {
    const float* x  = (const float*)d_in[0];   // [B,T,D] fp32
    const float* cb = (const float*)d_in[1];   // [K,D]   fp32
    float* out = (float*)d_out;

    char* ws = (char*)d_ws;
    f16*      ch    = (f16*)ws;                              // 524288 B
    float*    c2    = (float*)(ws + 524288);                 // 4096 B
    unsigned* count = (unsigned*)(ws + 528448);              // 4 B (padded)
    unsigned* list  = (unsigned*)(ws + 528512);              // 262144 B

    hipLaunchKernelGGL(vq_prep,   dim3(KCODES / 4), dim3(256), 0, stream, cb, ch, c2, count);
    hipLaunchKernelGGL(vq_main,   dim3(NTOK / 128), dim3(256), 0, stream,
                       x, ch, c2, cb, out, count, list);
    hipLaunchKernelGGL(vq_rescue, dim3(256),        dim3(256), 0, stream,
                       x, cb, c2, count, list, out);
}

// Round 3
// 227.831 us; speedup vs baseline: 1.2691x; 1.2691x over previous
//
#include <hip/hip_runtime.h>
#include <float.h>

// VectorQuantizer: B=16,T=4096,D=256,K=1024 fp32.
// Round 5: vq_main kept byte-identical to round 4 (reg-staged, swizzled,
//   double-buffered pipeline — it left the top-5).
//   vq_rescue reverted to the no-spill 8-token/iter blocking (round-2's
//   acc[4][32] needed 128 VGPRs vs 112 allocated -> scratch thrash, 186 us
//   at 3.8% VALU / 1.8% occupancy). Grid 256 -> 1024 + grid-stride.
//   Score space: score = x.c - 0.5*c2  (argmin d2 == argmax score).

typedef _Float16 f16;
typedef f16 f16x8 __attribute__((ext_vector_type(8)));
typedef f16 f16x4 __attribute__((ext_vector_type(4)));
typedef float f32x4 __attribute__((ext_vector_type(4)));

#define DDIM    256
#define KCODES  1024
#define NTOK    65536
#define SMARGIN 0.1f   // score-space margin; == 0.2 in d2 units (d2 gap = 2*score gap)

// swizzled LDS byte offset for (row, col-byte) in a 128-row x 128B tile
#define ASW(r, cbyte) ((r) * 128 + ((cbyte) ^ (((r) & 7) << 4)))

// ---------------- prep: codebook fp32->f16, c2, zero counter ----------------
__global__ __launch_bounds__(256) void vq_prep(const float* __restrict__ cb,
                                               f16* __restrict__ ch,
                                               float* __restrict__ c2,
                                               unsigned* __restrict__ count) {
    const int k    = blockIdx.x * 4 + (threadIdx.x >> 6);
    const int lane = threadIdx.x & 63;
    const float4 v = *(const float4*)(cb + (size_t)k * DDIM + 4 * lane);
    f16x4 h; h[0] = (f16)v.x; h[1] = (f16)v.y; h[2] = (f16)v.z; h[3] = (f16)v.w;
    *(f16x4*)(ch + (size_t)k * DDIM + 4 * lane) = h;
    float s = v.x * v.x + v.y * v.y + v.z * v.z + v.w * v.w;
    #pragma unroll
    for (int off = 32; off > 0; off >>= 1) s += __shfl_down(s, off, 64);
    if (lane == 0) c2[k] = s;
    if (blockIdx.x == 0 && threadIdx.x == 0) *count = 0u;
}

// ---------------- main: MFMA distances + fused argmax(score) + gather ----------------
// (byte-identical to round 4)
__global__ __launch_bounds__(256, 2) void vq_main(const float* __restrict__ xg,
                                                  const f16* __restrict__ ch,
                                                  const float* __restrict__ c2,
                                                  const float* __restrict__ cb,
                                                  float* __restrict__ out,
                                                  unsigned* __restrict__ count,
                                                  unsigned* __restrict__ list) {
    __shared__ f16   As[2 * 8192];             // 2 x (128 x 64) f16 = 32 KB
    __shared__ float c2s[KCODES];
    __shared__ float wmv[2][128];              // per code-half best score
    __shared__ int   wmi[2][128];
    __shared__ float wms[2][128];              // per code-half second score
    __shared__ float runv[128], runs[128];
    __shared__ int   runi[128];
    __shared__ int   idx_s[128];

    const int t    = threadIdx.x;
    const int wave = t >> 6, lane = t & 63;
    const int wm   = wave >> 1;                // code-half (M)
    const int tn   = wave & 1;                 // token-half (N)
    const int q    = lane >> 4;                // operand quad
    const int m16  = lane & 15;
    const int tok0 = blockIdx.x * 128;
    const int swz  = (m16 & 7) << 4;           // read-side swizzle (row&7 == m16&7)
    const int srow = t >> 3;                   // staging: rows srow + 32*i
    const int sc16 = t & 7;                    // staging: col granule (16B)

    // ---- load token B-fragments, fp32 -> f16 in registers (once) ----
    f16x8 bfrag[4][8];
    #pragma unroll
    for (int ti = 0; ti < 4; ++ti) {
        const size_t row = (size_t)(tok0 + tn * 64 + ti * 16 + m16) * DDIM;
        #pragma unroll
        for (int ks = 0; ks < 8; ++ks) {
            const float* p = xg + row + ks * 32 + q * 8;
            const float4 u0 = *(const float4*)(p);
            const float4 u1 = *(const float4*)(p + 4);
            f16x8 b;
            b[0] = (f16)u0.x; b[1] = (f16)u0.y; b[2] = (f16)u0.z; b[3] = (f16)u0.w;
            b[4] = (f16)u1.x; b[5] = (f16)u1.y; b[6] = (f16)u1.z; b[7] = (f16)u1.w;
            bfrag[ti][ks] = b;
        }
    }

    *(float4*)&c2s[t * 4] = *(const float4*)(c2 + t * 4);
    if (t < 128) { runv[t] = -FLT_MAX; runs[t] = -FLT_MAX; runi[t] = 0; }

    // prologue: issue stage (0,0) loads into regs
    f16x8 sreg[4];
    #pragma unroll
    for (int i = 0; i < 4; ++i)
        sreg[i] = *(const f16x8*)(ch + (size_t)(srow + 32 * i) * DDIM + sc16 * 8);
    __syncthreads();                           // c2s / runv init visible

    for (int nc = 0; nc < 8; ++nc) {
        f32x4 acc[4][4];                       // [ci][ti], init = -0.5*c2 (score space)
        #pragma unroll
        for (int ci = 0; ci < 4; ++ci) {
            f32x4 cv = *(const f32x4*)&c2s[nc * 128 + wm * 64 + ci * 16 + q * 4];
            cv = cv * -0.5f;
            #pragma unroll
            for (int ti = 0; ti < 4; ++ti) acc[ci][ti] = cv;
        }

        #pragma unroll
        for (int st = 0; st < 4; ++st) {       // BK=64 stages; buf parity == st&1
            // ---- write staged regs -> buf[st&1], swizzled (conflict-free) ----
            char* Ab = (char*)As + (st & 1) * 16384;
            #pragma unroll
            for (int i = 0; i < 4; ++i) {
                const int r = srow + 32 * i;
                *(f16x8*)(Ab + ASW(r, sc16 * 16)) = sreg[i];
            }
            // ---- issue next stage's loads (fly under this stage's MFMA) ----
            if (!(nc == 7 && st == 3)) {
                const int nn = nc + (st == 3 ? 1 : 0);
                const int ns = (st + 1) & 3;
                #pragma unroll
                for (int i = 0; i < 4; ++i)
                    sreg[i] = *(const f16x8*)(ch + (size_t)(nn * 128 + srow + 32 * i) * DDIM
                                              + ns * 64 + sc16 * 8);
            }
            __syncthreads();                   // buf[st&1] visible; dbuf covers WAR

            // ---- compute: ds_read (swizzled) + 32 MFMA ----
            const char* Ar = (const char*)As + (st & 1) * 16384;
            const int rbase = (wm * 64 + m16) * 128;
            #pragma unroll
            for (int kk = 0; kk < 2; ++kk) {
                const int col = ((kk << 6) | (q << 4)) ^ swz;
                f16x8 af[4];
                #pragma unroll
                for (int ci = 0; ci < 4; ++ci)
                    af[ci] = *(const f16x8*)(Ar + rbase + ci * 2048 + col);
                #pragma unroll
                for (int ci = 0; ci < 4; ++ci)
                    #pragma unroll
                    for (int ti = 0; ti < 4; ++ti)
                        acc[ci][ti] = __builtin_amdgcn_mfma_f32_16x16x32_f16(
                            af[ci], bfrag[ti][st * 2 + kk], acc[ci][ti], 0, 0, 0);
            }

            if (st == 3) {
                // ---- chunk epilogue: per-token top-2 (max score) over 128 codes ----
                const int kbase = nc * 128 + wm * 64;
                #pragma unroll
                for (int ti = 0; ti < 4; ++ti) {
                    float b1 = -FLT_MAX, b2 = -FLT_MAX; int i1 = 0;
                    #pragma unroll
                    for (int ci = 0; ci < 4; ++ci) {   // ascending code order
                        #pragma unroll
                        for (int r = 0; r < 4; ++r) {
                            const float v = acc[ci][ti][r];
                            const int   c = kbase + ci * 16 + q * 4 + r;
                            const bool gt = v > b1;    // strict: tie keeps lower index
                            b2 = fmaxf(b2, gt ? b1 : v);
                            i1 = gt ? c : i1;
                            b1 = gt ? v : b1;
                        }
                    }
                    #pragma unroll
                    for (int sft = 0; sft < 2; ++sft) {  // merge quads (l^16, l^32)
                        const int off = 16 << sft;
                        const float ob1 = __shfl_xor(b1, off, 64);
                        const float ob2 = __shfl_xor(b2, off, 64);
                        const int   oi1 = __shfl_xor(i1, off, 64);
                        const bool better = (ob1 > b1) || (ob1 == b1 && oi1 < i1);
                        b2 = fmaxf(fmaxf(b2, ob2), fminf(b1, ob1));
                        b1 = better ? ob1 : b1;
                        i1 = better ? oi1 : i1;
                    }
                    if (lane < 16) {
                        const int tl = tn * 64 + ti * 16 + m16;
                        wmv[wm][tl] = b1; wmi[wm][tl] = i1; wms[wm][tl] = b2;
                    }
                }
                __syncthreads();                // wmv visible
                if (t < 128) {                  // merge code-halves, fold into running
                    const float a1 = wmv[0][t], a2 = wms[0][t];
                    const int   ai = wmi[0][t];
                    const float b1_ = wmv[1][t], b2_ = wms[1][t];
                    const int   bi_ = wmi[1][t];
                    const bool bb = (b1_ > a1) || (b1_ == a1 && bi_ < ai);
                    const float c1 = bb ? b1_ : a1;
                    const int   ci_ = bb ? bi_ : ai;
                    const float cs = fmaxf(fmaxf(a2, b2_), fminf(a1, b1_));
                    const float r1 = runv[t];
                    runs[t] = fmaxf(fmaxf(runs[t], cs), fminf(r1, c1));
                    if (c1 > r1) { runv[t] = c1; runi[t] = ci_; }  // tie -> earlier chunk
                }
                // next chunk's first stage barrier orders the wmv rewrite
            }
        }
    }

    __syncthreads();
    if (t < 128) {
        idx_s[t] = runi[t];
        if (runv[t] - runs[t] < SMARGIN) {      // d2 gap = 2*(runv-runs) < 0.2
            const unsigned p = atomicAdd(count, 1u);
            list[p] = tok0 + t;
        }
    }
    __syncthreads();

    // gather epilogue: out[tok] = cb[argmin], coalesced float4
    #pragma unroll
    for (int i = 0; i < 32; ++i) {
        const int f   = i * 256 + t;           // 8192 float4 = 128 tok x 64
        const int tok = f >> 6, d4 = f & 63;
        const int code = idx_s[tok];
        const float4 v = *(const float4*)(cb + (size_t)code * DDIM + 4 * d4);
        *(float4*)(out + (size_t)(tok0 + tok) * DDIM + 4 * d4) = v;
    }
}

// ---------------- rescue: exact fp32 argmin for margin-flagged tokens ----------------
// 8 tokens/block-iter: acc[4][8] = 32 VGPRs (no spill — round-2's acc[4][32]
// spilled at VGPR=112 -> 186 us). Grid-stride over 1024 blocks.
// Per-(code,token) fmaf chain: d4-major ascending, .x->.w — verified order.
__global__ __launch_bounds__(256) void vq_rescue(const float* __restrict__ xg,
                                                 const float* __restrict__ cb,
                                                 const float* __restrict__ c2,
                                                 const unsigned* __restrict__ count,
                                                 const unsigned* __restrict__ list,
                                                 float* __restrict__ out) {
    __shared__ float xls[8][DDIM];             // 8 KB
    __shared__ float rv[4][8];
    __shared__ int   ri[4][8];
    __shared__ int   bidx[8];

    const int t = threadIdx.x;
    const int wave = t >> 6, lane = t & 63;
    const unsigned n = *count;

    for (unsigned base = blockIdx.x * 8; base < n; base += gridDim.x * 8) {
        const int nb = (int)min(8u, n - base);
        __syncthreads();                        // protect xls/rv/bidx reuse
        #pragma unroll
        for (int i = 0; i < 2; ++i) {
            const int f = t + 256 * i;          // 512 float4 slots
            const int row = f >> 6, d4 = f & 63;
            if (row < nb)
                *(float4*)&xls[row][4 * d4] =
                    *(const float4*)(xg + (size_t)list[base + row] * DDIM + 4 * d4);
        }
        __syncthreads();

        float acc[4][8];
        #pragma unroll
        for (int j = 0; j < 4; ++j)
            #pragma unroll
            for (int tk = 0; tk < 8; ++tk) acc[j][tk] = 0.0f;

        for (int d4 = 0; d4 < 64; ++d4) {
            float4 cv[4];
            #pragma unroll
            for (int j = 0; j < 4; ++j)
                cv[j] = *(const float4*)(cb + (size_t)(4 * t + j) * DDIM + 4 * d4);
            #pragma unroll
            for (int tk = 0; tk < 8; ++tk) {
                const float4 xv = *(const float4*)&xls[tk][4 * d4];
                #pragma unroll
                for (int j = 0; j < 4; ++j) {
                    float a = acc[j][tk];       // sequential .x->.w: verified order
                    a = fmaf(cv[j].x, xv.x, a);
                    a = fmaf(cv[j].y, xv.y, a);
                    a = fmaf(cv[j].z, xv.z, a);
                    a = fmaf(cv[j].w, xv.w, a);
                    acc[j][tk] = a;
                }
            }
        }

        // per-token argmin: thread's 4 codes -> wave butterfly -> cross-wave merge
        #pragma unroll
        for (int tk = 0; tk < 8; ++tk) {
            if (tk < nb) {
                float b1 = FLT_MAX; int i1 = 0;
                #pragma unroll
                for (int j = 0; j < 4; ++j) {   // codes 4t..4t+3 ascending
                    const float d = fmaf(-2.0f, acc[j][tk], c2[4 * t + j]);
                    if (d < b1) { b1 = d; i1 = 4 * t + j; }
                }
                #pragma unroll
                for (int off = 32; off > 0; off >>= 1) {
                    const float ov = __shfl_xor(b1, off, 64);
                    const int   oi = __shfl_xor(i1, off, 64);
                    if (ov < b1 || (ov == b1 && oi < i1)) { b1 = ov; i1 = oi; }
                }
                if (lane == 0) { rv[wave][tk] = b1; ri[wave][tk] = i1; }
            }
        }
        __syncthreads();
        if (t < 8 && t < nb) {                  // ascending wave order: same tiebreak
            float bv = rv[0][t]; int bi = ri[0][t];
            #pragma unroll
            for (int w = 1; w < 4; ++w)
                if (rv[w][t] < bv || (rv[w][t] == bv && ri[w][t] < bi)) {
                    bv = rv[w][t]; bi = ri[w][t];
                }
            bidx[t] = bi;
        }
        __syncthreads();

        #pragma unroll
        for (int i = 0; i < 2; ++i) {
            const int f = t + 256 * i;
            const int row = f >> 6, d4 = f & 63;
            if (row < nb) {
                const int code = bidx[row];
                const float4 v = *(const float4*)(cb + (size_t)code * DDIM + 4 * d4);
                *(float4*)(out + (size_t)list[base + row] * DDIM + 4 * d4) = v;
            }
        }
    }
}

extern "C" void kernel_launch(void* const* d_in, const int* in_sizes, int n_in,
                              void* d_out, int out_size, void* d_ws, size_t ws_size,
                              hipStream_t stream) {
    const float* x  = (const float*)d_in[0];   // [B,T,D] fp32
    const float* cb = (const float*)d_in[1];   // [K,D]   fp32
    float* out = (float*)d_out;

    char* ws = (char*)d_ws;
    f16*      ch    = (f16*)ws;                              // 524288 B
    float*    c2    = (float*)(ws + 524288);                 // 4096 B
    unsigned* count = (unsigned*)(ws + 528448);              // 4 B (padded)
    unsigned* list  = (unsigned*)(ws + 528512);              // 262144 B

    hipLaunchKernelGGL(vq_prep,   dim3(KCODES / 4), dim3(256), 0, stream, cb, ch, c2, count);
    hipLaunchKernelGGL(vq_main,   dim3(NTOK / 128), dim3(256), 0, stream,
                       x, ch, c2, cb, out, count, list);
    hipLaunchKernelGGL(vq_rescue, dim3(1024),       dim3(256), 0, stream,
                       x, cb, c2, count, list, out);
}